// Round 9
// baseline (116.245 us; speedup 1.0000x reference)
//
#include <hip/hip_runtime.h>
#include <hip/hip_bf16.h>

#define NUM_CLASS 21
#define EPSF 1e-6f
// Problem dims (fixed by setup_inputs): B=8, D=512, H=W=128 -> HW=16384
#define BATCH 8
#define DCH 512
#define HW 16384
#define NMFMA (BATCH * (DCH / 16))   // 256 mfma blocks: (b, 16-d group)

typedef __attribute__((ext_vector_type(8))) short bf16x8;   // 8 bf16 = 4 VGPR
typedef __attribute__((ext_vector_type(4))) float f32x4;

__device__ __forceinline__ float waveReduce(float v) {
    #pragma unroll
    for (int m = 1; m < 64; m <<= 1) v += __shfl_xor(v, m, 64);
    return v;
}

// ---------------------------------------------------------------------------
// Process one K-tile (32 p's, 8 per lane): build bf16 hi/lo feature fragment
// and two onehot A fragments (classes ln and ln+16), accumulate 4 MFMAs.
// k-mapping inside the fragment cancels because A and B use the same
// (lane,reg) positions; only C/D layout (m89-verified) must be correct.
// ---------------------------------------------------------------------------
__device__ __forceinline__ void procTile(
    float4 f0, float4 f1, int4 la, int4 lb, int ln,
    f32x4& acc0, f32x4& acc1, float& ss)
{
    bf16x8 hi, lo, a0, a1;
    const float fv[8] = {f0.x, f0.y, f0.z, f0.w, f1.x, f1.y, f1.z, f1.w};
    const int   lv[8] = {la.x, la.y, la.z, la.w, lb.x, lb.y, lb.z, lb.w};
    #pragma unroll
    for (int j = 0; j < 8; ++j) {
        const unsigned fb = __float_as_uint(fv[j]);
        hi[j] = (short)(fb >> 16);                       // truncate to bf16
        const float hif = __uint_as_float(fb & 0xFFFF0000u);
        const float lof = fv[j] - hif;                   // exact residual
        lo[j] = (short)(__float_as_uint(lof) >> 16);
        a0[j] = (lv[j] == ln)      ? (short)0x3F80 : (short)0;  // 1.0 bf16
        a1[j] = (lv[j] == ln + 16) ? (short)0x3F80 : (short)0;
        const float g = ((unsigned)lv[j] < NUM_CLASS) ? fv[j] : 0.0f;
        ss = fmaf(g, fv[j], ss);                         // valid-gated f^2
    }
    acc0 = __builtin_amdgcn_mfma_f32_16x16x32_bf16(a0, hi, acc0, 0, 0, 0);
    acc0 = __builtin_amdgcn_mfma_f32_16x16x32_bf16(a0, lo, acc0, 0, 0, 0);
    acc1 = __builtin_amdgcn_mfma_f32_16x16x32_bf16(a1, hi, acc1, 0, 0, 0);
    acc1 = __builtin_amdgcn_mfma_f32_16x16x32_bf16(a1, lo, acc1, 0, 0, 0);
}

// ---------------------------------------------------------------------------
// MFMA scatter kernel: one block per (b, d-group of 16). Wave w owns
// p in [w*4096, (w+1)*4096) (128 K-tiles), accumulating S[c, d0..d0+15]
// partials in AGPR/VGPR; 2-deep tile ring keeps >=16KB/block in flight.
// No LDS in the hot loop (gfx950 LDS RMW chains were the 22us residual).
// B-frag lane l: F[D0+(l&15)][P + (l>>4)*8 + j]; A-frag lane l: row l&15.
// ---------------------------------------------------------------------------
__global__ __launch_bounds__(256) void car_mfma_kernel(
    const float* __restrict__ features, const int* __restrict__ label,
    float* __restrict__ class_sum, float* __restrict__ ss_parts)
{
    __shared__ float comb[4][512];
    __shared__ float red[4];
    const int t = threadIdx.x;
    const int lane = t & 63;
    const int wave = t >> 6;
    const int ln = lane & 15;
    const int l4 = lane >> 4;

    const int bid = blockIdx.x;
    const int dg = bid & 31;
    const int b  = bid >> 5;
    const int D0 = dg * 16;

    const float* __restrict__ frow = features + ((size_t)(b * DCH + D0 + ln)) * HW;
    const int*   __restrict__ lrow = label + (size_t)b * HW;

    const int NT = 128;                      // K-tiles per wave (4096 p)
    int pbase = wave * 4096 + l4 * 8;

    f32x4 acc0 = {0.f, 0.f, 0.f, 0.f};
    f32x4 acc1 = {0.f, 0.f, 0.f, 0.f};
    float ss = 0.0f;

    // preload tiles 0,1
    float4 f0a = *(const float4*)(frow + pbase);
    float4 f1a = *(const float4*)(frow + pbase + 4);
    int4   laa = *(const int4*)(lrow + pbase);
    int4   lba = *(const int4*)(lrow + pbase + 4);
    float4 f0b = *(const float4*)(frow + pbase + 32);
    float4 f1b = *(const float4*)(frow + pbase + 36);
    int4   lab = *(const int4*)(lrow + pbase + 32);
    int4   lbb = *(const int4*)(lrow + pbase + 36);

    #pragma unroll 1
    for (int kt = 0; kt < NT - 2; kt += 2) {
        procTile(f0a, f1a, laa, lba, ln, acc0, acc1, ss);
        f0a = *(const float4*)(frow + pbase + 64);
        f1a = *(const float4*)(frow + pbase + 68);
        laa = *(const int4*)(lrow + pbase + 64);
        lba = *(const int4*)(lrow + pbase + 68);
        procTile(f0b, f1b, lab, lbb, ln, acc0, acc1, ss);
        f0b = *(const float4*)(frow + pbase + 96);
        f1b = *(const float4*)(frow + pbase + 100);
        lab = *(const int4*)(lrow + pbase + 96);
        lbb = *(const int4*)(lrow + pbase + 100);
        pbase += 64;
    }
    procTile(f0a, f1a, laa, lba, ln, acc0, acc1, ss);
    procTile(f0b, f1b, lab, lbb, ln, acc0, acc1, ss);

    // Combine the 4 waves' partial accumulators via LDS.
    #pragma unroll
    for (int r = 0; r < 4; ++r) {
        comb[wave][lane * 8 + r]     = acc0[r];
        comb[wave][lane * 8 + 4 + r] = acc1[r];
    }
    ss = waveReduce(ss);
    if (lane == 0) red[wave] = ss;
    __syncthreads();

    if (wave == 0) {
        // C/D layout (m89-verified): col = lane&15 (d), row = (lane>>4)*4+reg (c)
        float* __restrict__ outp = class_sum + (size_t)b * NUM_CLASS * DCH;
        #pragma unroll
        for (int r = 0; r < 4; ++r) {
            const int i0 = lane * 8 + r;
            const float v0 = comb[0][i0] + comb[1][i0] + comb[2][i0] + comb[3][i0];
            const int c0 = l4 * 4 + r;
            outp[(size_t)c0 * DCH + D0 + ln] = v0;
            const int i1 = lane * 8 + 4 + r;
            const float v1 = comb[0][i1] + comb[1][i1] + comb[2][i1] + comb[3][i1];
            const int c1 = 16 + l4 * 4 + r;
            if (c1 < NUM_CLASS) outp[(size_t)c1 * DCH + D0 + ln] = v1;
        }
        if (t == 0) ss_parts[bid] = red[0] + red[1] + red[2] + red[3];
    }
}

// ---------------------------------------------------------------------------
// Counts kernel (proven round-3 path): per-batch class histogram + valid
// count via per-wave private LDS copies, per-element adjacent RMW.
// ---------------------------------------------------------------------------
__global__ __launch_bounds__(256) void car_counts_kernel(
    const int* __restrict__ label, float* __restrict__ counts,
    float* __restrict__ total_parts)
{
    __shared__ float sm[4][NUM_CLASS * 64];
    __shared__ float red[4];
    const int t = threadIdx.x;
    const int lane = t & 63;
    const int wave = t >> 6;
    const int b = blockIdx.x;

    float* __restrict__ smw = &sm[wave][0];
    for (int i = lane; i < NUM_CLASS * 64; i += 64) smw[i] = 0.0f;

    const int4* __restrict__ lrow = (const int4*)(label + (size_t)b * HW);
    float tv = 0.0f;
    #pragma unroll 2
    for (int i = 0; i < 16; ++i) {
        int4 l = lrow[i * 256 + t];
        if (l.x != 255) tv += 1.0f;
        if ((unsigned)l.x < NUM_CLASS) { float v = smw[l.x * 64 + lane]; smw[l.x * 64 + lane] = v + 1.0f; }
        if (l.y != 255) tv += 1.0f;
        if ((unsigned)l.y < NUM_CLASS) { float v = smw[l.y * 64 + lane]; smw[l.y * 64 + lane] = v + 1.0f; }
        if (l.z != 255) tv += 1.0f;
        if ((unsigned)l.z < NUM_CLASS) { float v = smw[l.z * 64 + lane]; smw[l.z * 64 + lane] = v + 1.0f; }
        if (l.w != 255) tv += 1.0f;
        if ((unsigned)l.w < NUM_CLASS) { float v = smw[l.w * 64 + lane]; smw[l.w * 64 + lane] = v + 1.0f; }
    }
    __syncthreads();

    for (int c = wave; c < NUM_CLASS; c += 4) {
        const int idx = c * 64 + lane;
        float v = sm[0][idx] + sm[1][idx] + sm[2][idx] + sm[3][idx];
        v = waveReduce(v);
        if (lane == 0) counts[b * NUM_CLASS + c] = v;
    }

    tv = waveReduce(tv);
    if (lane == 0) red[wave] = tv;
    __syncthreads();
    if (t == 0) total_parts[b] = red[0] + red[1] + red[2] + red[3];
}

// ---------------------------------------------------------------------------
// Finalize (1 block, 1024 threads).
//  0: sum ss_parts[256].
//  A: centers, intra correction corr = sum cen*(n*cen - 2S); batch-mean cm.
//  C: per-class norms of cm.   D: 21x21 cosine sim -> inter loss.
//  out[0] = (ss + corr)/(total+eps); out[1] = sum relu(sim-.5)/(21+eps).
// ---------------------------------------------------------------------------
__global__ __launch_bounds__(1024) void car_finalize_kernel(
    const float* __restrict__ class_sum, const float* __restrict__ counts,
    const float* __restrict__ ss_parts, const float* __restrict__ total_parts,
    float* __restrict__ out)
{
    __shared__ float cm[NUM_CLASS * DCH];
    __shared__ float norms[NUM_CLASS];
    __shared__ float redC[16];
    __shared__ float redS[16];
    __shared__ float redB[16];
    const int t = threadIdx.x;
    const int lane = t & 63;
    const int wave = t >> 6;

    float ssp = (t < NMFMA) ? ss_parts[t] : 0.0f;

    float corr = 0.0f;
    for (int p = t; p < NUM_CLASS * DCH; p += 1024) {
        const int c = p >> 9;
        float s = 0.0f;
        #pragma unroll
        for (int b = 0; b < BATCH; ++b) {
            float S = class_sum[(size_t)b * NUM_CLASS * DCH + p];
            float n = counts[b * NUM_CLASS + c];
            float cen = S / (n + EPSF);
            corr += cen * (n * cen - 2.0f * S);
            s += cen;
        }
        cm[p] = s * (1.0f / BATCH);
    }
    corr = waveReduce(corr);
    ssp  = waveReduce(ssp);
    if (lane == 0) { redC[wave] = corr; redS[wave] = ssp; }
    __syncthreads();

    for (int c = wave; c < NUM_CLASS; c += 16) {
        float s = 0.0f;
        #pragma unroll
        for (int k = 0; k < DCH / 64; ++k) {
            float v = cm[c * DCH + k * 64 + lane];
            s += v * v;
        }
        s = waveReduce(s);
        if (lane == 0) norms[c] = fmaxf(sqrtf(s), 1e-12f);
    }
    __syncthreads();

    float interAcc = 0.0f;
    for (int p = wave; p < NUM_CLASS * NUM_CLASS; p += 16) {
        const int c1 = p / NUM_CLASS;
        const int c2 = p % NUM_CLASS;
        if (c1 == c2) continue;
        float s = 0.0f;
        #pragma unroll
        for (int k = 0; k < DCH / 64; ++k)
            s += cm[c1 * DCH + k * 64 + lane] * cm[c2 * DCH + k * 64 + lane];
        s = waveReduce(s);
        if (lane == 0) {
            float sim = s / (norms[c1] * norms[c2]);
            interAcc += fmaxf(sim - 0.5f, 0.0f);
        }
    }
    if (lane == 0) redB[wave] = interAcc;
    __syncthreads();

    if (t == 0) {
        float corrT = 0.0f, interT = 0.0f, ssT = 0.0f, tot = 0.0f;
        #pragma unroll
        for (int w = 0; w < 16; ++w) { corrT += redC[w]; interT += redB[w]; ssT += redS[w]; }
        #pragma unroll
        for (int b = 0; b < BATCH; ++b) tot += total_parts[b];
        out[0] = (ssT + corrT) / (tot + EPSF);
        out[1] = interT / ((float)NUM_CLASS + EPSF);
    }
}

extern "C" void kernel_launch(void* const* d_in, const int* in_sizes, int n_in,
                              void* d_out, int out_size, void* d_ws, size_t ws_size,
                              hipStream_t stream) {
    const float* features = (const float*)d_in[0];
    const int*   label    = (const int*)d_in[1];
    float* out = (float*)d_out;

    // ws layout (floats):
    //   [0 .. 256)           ss_parts (one per mfma block)
    //   [256 .. 264)         total_parts
    //   [264 .. 432)         counts (8*21)
    //   [512 .. 86528)       class_sum[8][21][512]
    float* ws          = (float*)d_ws;
    float* ss_parts    = ws + 0;
    float* total_parts = ws + 256;
    float* counts      = ws + 264;
    float* class_sum   = ws + 512;

    car_counts_kernel<<<BATCH, 256, 0, stream>>>(label, counts, total_parts);
    car_mfma_kernel<<<NMFMA, 256, 0, stream>>>(features, label, class_sum, ss_parts);
    car_finalize_kernel<<<1, 1024, 0, stream>>>(class_sum, counts, ss_parts, total_parts, out);
}

// Round 10
// 78.243 us; speedup vs baseline: 1.4857x; 1.4857x over previous
//
#include <hip/hip_runtime.h>
#include <hip/hip_bf16.h>

#define NUM_CLASS 21
#define IGNORE_L 255
#define EPSF 1e-6f
// Problem dims (fixed by setup_inputs): B=8, D=512, H=W=128 -> HW=16384
#define BATCH 8
#define DCH 512
#define HW 16384
#define NPAIRS (BATCH * DCH / 2)   // 2048 scatter blocks (one per d-pair)

__device__ __forceinline__ float waveReduce(float v) {
    #pragma unroll
    for (int m = 1; m < 64; m <<= 1) v += __shfl_xor(v, m, 64);
    return v;
}

// Batched float2 LDS RMW for one quad (rows d0,d0+1 in one b64 slot).
// slot = lane: two DIFFERENT lanes can never alias (addr = class*64+lane),
// so the only hazard is in-thread duplicate classes. Those are merged
// branchlessly: for each pair i<j with ci==cj, g_j += g_i, g_i = 0. With
// source order R,R,R,R / add / W,W,W,W (compiler must preserve: may-alias),
// duplicate addresses read the same value and the LAST write carries the
// merged sum -> race-free, ONE lgkmcnt stall per quad instead of 4 serial
// RMW chains. Invalid labels clamp to class 0 with g=0.
__device__ __forceinline__ void rmwq(float2* __restrict__ smw, int lane,
                                     float4 fa, float4 fb, int4 l, float& ss) {
    const bool v0 = (unsigned)l.x < NUM_CLASS;
    const bool v1 = (unsigned)l.y < NUM_CLASS;
    const bool v2 = (unsigned)l.z < NUM_CLASS;
    const bool v3 = (unsigned)l.w < NUM_CLASS;
    const int c0 = v0 ? l.x : 0;
    const int c1 = v1 ? l.y : 0;
    const int c2 = v2 ? l.z : 0;
    const int c3 = v3 ? l.w : 0;
    float g0x = v0 ? fa.x : 0.f, g0y = v0 ? fb.x : 0.f;
    float g1x = v1 ? fa.y : 0.f, g1y = v1 ? fb.y : 0.f;
    float g2x = v2 ? fa.z : 0.f, g2y = v2 ? fb.z : 0.f;
    float g3x = v3 ? fa.w : 0.f, g3y = v3 ? fb.w : 0.f;

    // ss uses pre-merge gated values: f^2 for valid elements of both rows.
    ss = fmaf(g0x, fa.x, ss); ss = fmaf(g0y, fb.x, ss);
    ss = fmaf(g1x, fa.y, ss); ss = fmaf(g1y, fb.y, ss);
    ss = fmaf(g2x, fa.z, ss); ss = fmaf(g2y, fb.z, ss);
    ss = fmaf(g3x, fa.w, ss); ss = fmaf(g3y, fb.w, ss);

    // Duplicate merge (later element absorbs earlier; earlier zeroed).
    if (c1 == c0) { g1x += g0x; g1y += g0y; g0x = 0.f; g0y = 0.f; }
    if (c2 == c0) { g2x += g0x; g2y += g0y; g0x = 0.f; g0y = 0.f; }
    if (c2 == c1) { g2x += g1x; g2y += g1y; g1x = 0.f; g1y = 0.f; }
    if (c3 == c0) { g3x += g0x; g3y += g0y; g0x = 0.f; g0y = 0.f; }
    if (c3 == c1) { g3x += g1x; g3y += g1y; g1x = 0.f; g1y = 0.f; }
    if (c3 == c2) { g3x += g2x; g3y += g2y; g2x = 0.f; g2y = 0.f; }

    const int a0 = c0 * 64 + lane;
    const int a1 = c1 * 64 + lane;
    const int a2 = c2 * 64 + lane;
    const int a3 = c3 * 64 + lane;
    float2 w0 = smw[a0];
    float2 w1 = smw[a1];
    float2 w2 = smw[a2];
    float2 w3 = smw[a3];
    w0.x += g0x; w0.y += g0y;
    w1.x += g1x; w1.y += g1y;
    w2.x += g2x; w2.y += g2y;
    w3.x += g3x; w3.y += g3y;
    smw[a0] = w0;
    smw[a1] = w1;
    smw[a2] = w2;
    smw[a3] = w3;
}

// ---------------------------------------------------------------------------
// Fused kernel: blocks [0,8) per-batch counts; blocks [8, 8+NPAIRS) handle a
// (b, d0=2*pair) ROW PAIR: labels read once per pair, float2 slots halve DS
// instructions. Per-wave private LDS copies (no atomics; gfx950 ds_add_f32
// ~lane-serial). 4-deep prefetch ring covers HBM latency at 3 blocks/CU.
// ---------------------------------------------------------------------------
__global__ __launch_bounds__(256) void car_fused_kernel(
    const float* __restrict__ features, const int* __restrict__ label,
    float* __restrict__ class_sum, float* __restrict__ ss_parts,
    float* __restrict__ counts, float* __restrict__ total_parts)
{
    __shared__ float2 sm[4][NUM_CLASS * 64];
    __shared__ float red[4];
    const int t = threadIdx.x;
    const int lane = t & 63;
    const int wave = t >> 6;

    float2* __restrict__ smw = &sm[wave][0];
    #pragma unroll
    for (int i = lane; i < NUM_CLASS * 64; i += 64) smw[i] = make_float2(0.f, 0.f);
    // no sync: each wave touches only its own copy until the merge

    if (blockIdx.x < BATCH) {
        // ---- counts path: fa = ones, fb = 0; slot .x accumulates count ----
        const int b = blockIdx.x;
        const int4* __restrict__ lrow = (const int4*)(label + (size_t)b * HW);
        const float4 f1 = {1.f, 1.f, 1.f, 1.f};
        const float4 f0 = {0.f, 0.f, 0.f, 0.f};
        float tv = 0.0f;
        #pragma unroll 2
        for (int i = 0; i < 16; ++i) {
            int4 l = lrow[i * 256 + t];
            rmwq(smw, lane, f1, f0, l, tv);   // tv += 1 per valid
        }
        __syncthreads();
        for (int c = wave; c < NUM_CLASS; c += 4) {
            const float4 vA = *(const float4*)((const float*)&sm[lane >> 5][c * 64] + (lane & 31) * 4);
            const float4 vB = *(const float4*)((const float*)&sm[2 + (lane >> 5)][c * 64] + (lane & 31) * 4);
            float px = (vA.x + vA.z) + (vB.x + vB.z);
            px = waveReduce(px);
            if (lane == 0) counts[b * NUM_CLASS + c] = px;
        }
        tv = waveReduce(tv);
        if (lane == 0) red[wave] = tv;
        __syncthreads();
        if (t == 0) total_parts[b] = red[0] + red[1] + red[2] + red[3];
        return;
    }

    // ---- scatter path: row pair (b, d0), (b, d0+1) ----
    const int r = blockIdx.x - BATCH;          // 0..NPAIRS-1
    const int b = r >> 8;
    const int d0 = (r & 255) * 2;
    const float4* __restrict__ frow0 = (const float4*)(features + ((size_t)b * DCH + d0) * HW);
    const float4* __restrict__ frow1 = (const float4*)(features + ((size_t)b * DCH + d0 + 1) * HW);
    const int4* __restrict__ lrow = (const int4*)(label + (size_t)b * HW);

    // 4-deep prefetch ring (named regs; runtime-indexed arrays would spill).
    float4 A0 = frow0[0 * 256 + t], B0 = frow1[0 * 256 + t];
    float4 A1 = frow0[1 * 256 + t], B1 = frow1[1 * 256 + t];
    float4 A2 = frow0[2 * 256 + t], B2 = frow1[2 * 256 + t];
    float4 A3 = frow0[3 * 256 + t], B3 = frow1[3 * 256 + t];
    int4 L0 = lrow[0 * 256 + t], L1 = lrow[1 * 256 + t];
    int4 L2 = lrow[2 * 256 + t], L3 = lrow[3 * 256 + t];
    float ss = 0.0f;

    #pragma unroll 1
    for (int i = 0; i < 12; i += 4) {
        rmwq(smw, lane, A0, B0, L0, ss);
        A0 = frow0[(i + 4) * 256 + t]; B0 = frow1[(i + 4) * 256 + t]; L0 = lrow[(i + 4) * 256 + t];
        rmwq(smw, lane, A1, B1, L1, ss);
        A1 = frow0[(i + 5) * 256 + t]; B1 = frow1[(i + 5) * 256 + t]; L1 = lrow[(i + 5) * 256 + t];
        rmwq(smw, lane, A2, B2, L2, ss);
        A2 = frow0[(i + 6) * 256 + t]; B2 = frow1[(i + 6) * 256 + t]; L2 = lrow[(i + 6) * 256 + t];
        rmwq(smw, lane, A3, B3, L3, ss);
        A3 = frow0[(i + 7) * 256 + t]; B3 = frow1[(i + 7) * 256 + t]; L3 = lrow[(i + 7) * 256 + t];
    }
    rmwq(smw, lane, A0, B0, L0, ss);
    rmwq(smw, lane, A1, B1, L1, ss);
    rmwq(smw, lane, A2, B2, L2, ss);
    rmwq(smw, lane, A3, B3, L3, ss);
    __syncthreads();

    // Merge 4 wave-copies x 64 slots per class.
    // Two b128 reads/class cover all 4 copies; .x/.z = row d0, .y/.w = d0+1.
    float* __restrict__ out_base = class_sum + (size_t)b * NUM_CLASS * DCH + d0;
    for (int c = wave; c < NUM_CLASS; c += 4) {
        const float4 vA = *(const float4*)((const float*)&sm[lane >> 5][c * 64] + (lane & 31) * 4);
        const float4 vB = *(const float4*)((const float*)&sm[2 + (lane >> 5)][c * 64] + (lane & 31) * 4);
        float px = (vA.x + vA.z) + (vB.x + vB.z);
        float py = (vA.y + vA.w) + (vB.y + vB.w);
        #pragma unroll
        for (int m = 1; m < 64; m <<= 1) {
            px += __shfl_xor(px, m, 64);
            py += __shfl_xor(py, m, 64);
        }
        if (lane == 0) *(float2*)&out_base[(size_t)c * DCH] = make_float2(px, py);
    }

    ss = waveReduce(ss);
    if (lane == 0) red[wave] = ss;
    __syncthreads();
    if (t == 0) ss_parts[r] = red[0] + red[1] + red[2] + red[3];
}

// ---------------------------------------------------------------------------
// Finalize (1 block, 1024 threads / 16 waves).
//  0: sum ss_parts[2048].
//  A: centers, intra correction corr = sum cen*(n*cen - 2S); batch-mean cm.
//  C: per-class norms of cm.   D: 21x21 cosine sim -> inter loss.
//  out[0] = (ss + corr)/(total+eps); out[1] = sum relu(sim-.5)/(21+eps).
// ---------------------------------------------------------------------------
__global__ __launch_bounds__(1024) void car_finalize_kernel(
    const float* __restrict__ class_sum, const float* __restrict__ counts,
    const float* __restrict__ ss_parts, const float* __restrict__ total_parts,
    float* __restrict__ out)
{
    __shared__ float cm[NUM_CLASS * DCH];
    __shared__ float norms[NUM_CLASS];
    __shared__ float redC[16];
    __shared__ float redS[16];
    __shared__ float redB[16];
    const int t = threadIdx.x;
    const int lane = t & 63;
    const int wave = t >> 6;

    float ssp = 0.0f;
    #pragma unroll
    for (int i = 0; i < NPAIRS / 1024; ++i) ssp += ss_parts[i * 1024 + t];

    float corr = 0.0f;
    for (int p = t; p < NUM_CLASS * DCH; p += 1024) {
        const int c = p >> 9;
        float s = 0.0f;
        #pragma unroll
        for (int b = 0; b < BATCH; ++b) {
            float S = class_sum[(size_t)b * NUM_CLASS * DCH + p];
            float n = counts[b * NUM_CLASS + c];
            float cen = S / (n + EPSF);
            corr += cen * (n * cen - 2.0f * S);
            s += cen;
        }
        cm[p] = s * (1.0f / BATCH);
    }
    corr = waveReduce(corr);
    ssp  = waveReduce(ssp);
    if (lane == 0) { redC[wave] = corr; redS[wave] = ssp; }
    __syncthreads();

    for (int c = wave; c < NUM_CLASS; c += 16) {
        float s = 0.0f;
        #pragma unroll
        for (int k = 0; k < DCH / 64; ++k) {
            float v = cm[c * DCH + k * 64 + lane];
            s += v * v;
        }
        s = waveReduce(s);
        if (lane == 0) norms[c] = fmaxf(sqrtf(s), 1e-12f);
    }
    __syncthreads();

    float interAcc = 0.0f;
    for (int p = wave; p < NUM_CLASS * NUM_CLASS; p += 16) {
        const int c1 = p / NUM_CLASS;
        const int c2 = p % NUM_CLASS;
        if (c1 == c2) continue;
        float s = 0.0f;
        #pragma unroll
        for (int k = 0; k < DCH / 64; ++k)
            s += cm[c1 * DCH + k * 64 + lane] * cm[c2 * DCH + k * 64 + lane];
        s = waveReduce(s);
        if (lane == 0) {
            float sim = s / (norms[c1] * norms[c2]);
            interAcc += fmaxf(sim - 0.5f, 0.0f);
        }
    }
    if (lane == 0) redB[wave] = interAcc;
    __syncthreads();

    if (t == 0) {
        float corrT = 0.0f, interT = 0.0f, ssT = 0.0f, tot = 0.0f;
        #pragma unroll
        for (int w = 0; w < 16; ++w) { corrT += redC[w]; interT += redB[w]; ssT += redS[w]; }
        #pragma unroll
        for (int b = 0; b < BATCH; ++b) tot += total_parts[b];
        out[0] = (ssT + corrT) / (tot + EPSF);
        out[1] = interT / ((float)NUM_CLASS + EPSF);
    }
}

extern "C" void kernel_launch(void* const* d_in, const int* in_sizes, int n_in,
                              void* d_out, int out_size, void* d_ws, size_t ws_size,
                              hipStream_t stream) {
    const float* features = (const float*)d_in[0];
    const int*   label    = (const int*)d_in[1];
    float* out = (float*)d_out;

    // ws layout (floats):
    //   [0 .. 2048)          ss_parts (one per scatter block)
    //   [2048 .. 2056)       total_parts
    //   [2056 .. 2224)       counts (8*21)
    //   [2304 .. 88320)      class_sum[8][21][512]
    float* ws          = (float*)d_ws;
    float* ss_parts    = ws + 0;
    float* total_parts = ws + 2048;
    float* counts      = ws + 2056;
    float* class_sum   = ws + 2304;

    car_fused_kernel<<<NPAIRS + BATCH, 256, 0, stream>>>(
        features, label, class_sum, ss_parts, counts, total_parts);
    car_finalize_kernel<<<1, 1024, 0, stream>>>(class_sum, counts, ss_parts, total_parts, out);
}